// Round 7
// baseline (483.440 us; speedup 1.0000x reference)
//
#include <hip/hip_runtime.h>
#include <hip/hip_bf16.h>

#define B_ 8
#define C_ 256
#define N_ 4096
#define D_ 16
#define TWO_C 512

typedef __bf16 bf16x8 __attribute__((ext_vector_type(8)));
typedef __bf16 bf16x4 __attribute__((ext_vector_type(4)));
typedef float f32x4 __attribute__((ext_vector_type(4)));
typedef unsigned short u16x4 __attribute__((ext_vector_type(4)));

static __device__ __forceinline__ unsigned short f2bf_rtn(float f) {
    unsigned int u = __builtin_bit_cast(unsigned int, f);
    u += 0x7fffu + ((u >> 16) & 1u);
    return (unsigned short)(u >> 16);
}

__device__ __forceinline__ void gld16(const void* g, void* l) {
    __builtin_amdgcn_global_load_lds(
        (const __attribute__((address_space(1))) unsigned int*)g,
        (__attribute__((address_space(3))) unsigned int*)l, 16, 0, 0);
}

__device__ __forceinline__ f32x4 expv(f32x4 e) {
    f32x4 r = { __expf(e[0]), __expf(e[1]), __expf(e[2]), __expf(e[3]) };
    return r;
}

#define MF(K, Q) __builtin_amdgcn_mfma_f32_16x16x32_bf16((K), (Q), zerov, 0, 0, 0)

// ---------------------------------------------------------------------------
// Kernel 0: Wv1/Wv2 -> bf16 stacked [512][256]. grid = 64 blocks of 256.
// ---------------------------------------------------------------------------
__global__ __launch_bounds__(256) void wconv(
    const float* __restrict__ Wv1, const float* __restrict__ Wv2,
    unsigned short* __restrict__ Wbf)
{
    const int i = blockIdx.x * 256 + threadIdx.x;   // f32x4 group, 16384 total
    f32x4 a = ((const f32x4*)Wv1)[i];
    f32x4 b = ((const f32x4*)Wv2)[i];
    u16x4 ua = { f2bf_rtn(a[0]), f2bf_rtn(a[1]), f2bf_rtn(a[2]), f2bf_rtn(a[3]) };
    u16x4 ub = { f2bf_rtn(b[0]), f2bf_rtn(b[1]), f2bf_rtn(b[2]), f2bf_rtn(b[3]) };
    ((u16x4*)Wbf)[i] = ua;
    ((u16x4*)Wbf)[16384 + i] = ub;
}

// ---------------------------------------------------------------------------
// Kernel 1a: partial q/k over a 128-wide c-chunk + side-write x as bf16
// TRANSPOSED xbfT[b][n][512] (c-contiguous). xbfT lives in the att region of
// d_out (fully overwritten later by fused_pv). grid = B*16*4 = 512 blocks.
// ---------------------------------------------------------------------------
__global__ __launch_bounds__(256) void qk_part(
    const float* __restrict__ x1, const float* __restrict__ x2,
    const float* __restrict__ Wq, const float* __restrict__ Wk,
    float* __restrict__ pq, float* __restrict__ pk,
    unsigned short* __restrict__ xbfT)
{
    const int tid = threadIdx.x;
    const int bid = blockIdx.x;
    const int ch = bid & 3;
    const int nt = (bid >> 2) & 15;
    const int b  = bid >> 6;
    const int n  = nt * 256 + tid;

    const float* xs  = (ch < 2) ? x1 : x2;
    const int xoff = (ch & 1) * 128;
    const int wcol = ch * 128;

    const float* px = xs + ((size_t)b * C_ + xoff) * N_ + n;
    unsigned short* xT = xbfT + ((size_t)b * N_ + n) * TWO_C + wcol;

    float aq[D_], ak[D_];
#pragma unroll
    for (int d = 0; d < D_; ++d) { aq[d] = 0.f; ak[d] = 0.f; }

    for (int c8 = 0; c8 < 16; ++c8) {
        unsigned short xb[8];
#pragma unroll
        for (int j = 0; j < 8; ++j) {
            const int c = c8 * 8 + j;
            float xv = px[(size_t)c * N_];
            xb[j] = f2bf_rtn(xv);
#pragma unroll
            for (int d = 0; d < D_; ++d) {
                aq[d] += Wq[d * TWO_C + wcol + c] * xv;
                ak[d] += Wk[d * TWO_C + wcol + c] * xv;
            }
        }
        u16x4 lo = { xb[0], xb[1], xb[2], xb[3] };
        u16x4 hi = { xb[4], xb[5], xb[6], xb[7] };
        *(u16x4*)(xT + c8 * 8)     = lo;
        *(u16x4*)(xT + c8 * 8 + 4) = hi;
    }

    f32x4* q4 = (f32x4*)pq + (size_t)ch * B_ * N_ * 4 + ((size_t)b * N_ + n) * 4;
    f32x4* k4 = (f32x4*)pk + (size_t)ch * B_ * N_ * 4 + ((size_t)b * N_ + n) * 4;
#pragma unroll
    for (int j = 0; j < 4; ++j) {
        f32x4 tq = { aq[4*j], aq[4*j+1], aq[4*j+2], aq[4*j+3] };
        f32x4 tk = { ak[4*j], ak[4*j+1], ak[4*j+2], ak[4*j+3] };
        q4[j] = tq;
        k4[j] = tk;
    }
}

// ---------------------------------------------------------------------------
// Kernel 1b: reduce 4 partials + bias, emit bf16 q/k in [B][N][32] layout
// (d = 16..31 zero-padded for the K=32 MFMA). grid = 512 blocks of 256.
// ---------------------------------------------------------------------------
__global__ __launch_bounds__(256) void qk_reduce(
    const float* __restrict__ pq, const float* __restrict__ pk,
    const float* __restrict__ bq, const float* __restrict__ bk,
    unsigned short* __restrict__ qbf, unsigned short* __restrict__ kbf)
{
    const int tg = blockIdx.x * 256 + threadIdx.x;  // f32x4 group index
    const int row = tg >> 2;                        // b*N + n
    const int d4  = tg & 3;
    const f32x4* pq4 = (const f32x4*)pq;
    const f32x4* pk4 = (const f32x4*)pk;
    f32x4 q = ((const f32x4*)bq)[d4];
    f32x4 k = ((const f32x4*)bk)[d4];
    const size_t stride = (size_t)B_ * N_ * 4;
#pragma unroll
    for (int ch = 0; ch < 4; ++ch) {
        q += pq4[ch * stride + tg];
        k += pk4[ch * stride + tg];
    }
    u16x4 qo = { f2bf_rtn(q[0]), f2bf_rtn(q[1]), f2bf_rtn(q[2]), f2bf_rtn(q[3]) };
    u16x4 ko = { f2bf_rtn(k[0]), f2bf_rtn(k[1]), f2bf_rtn(k[2]), f2bf_rtn(k[3]) };
    u16x4 z  = { 0, 0, 0, 0 };
    *(u16x4*)(qbf + (size_t)row * 32 + d4 * 4)      = qo;
    *(u16x4*)(qbf + (size_t)row * 32 + 16 + d4 * 4) = z;
    *(u16x4*)(kbf + (size_t)row * 32 + d4 * 4)      = ko;
    *(u16x4*)(kbf + (size_t)row * 32 + 16 + d4 * 4) = z;
}

// ---------------------------------------------------------------------------
// Kernel 2: v = Wv @ x + bv via MFMA, LDS-free. grid = 1024 blocks of 256.
// ---------------------------------------------------------------------------
__global__ __launch_bounds__(256) void v_mfma(
    const unsigned short* __restrict__ Wbf,
    const unsigned short* __restrict__ xbfT,
    const float* __restrict__ bv1, const float* __restrict__ bv2,
    unsigned short* __restrict__ vstack)
{
    const int tid  = threadIdx.x;
    const int lane = tid & 63;
    const int wid  = tid >> 6;
    const int bid  = blockIdx.x;
    const int b    = bid >> 7;
    const int half = (bid >> 6) & 1;
    const int n0   = (bid & 63) * 64;
    const int col  = lane & 15;
    const int grp  = lane >> 4;
    const int koff = grp * 8;

    const unsigned short* pa[4];
    const unsigned short* pb[4];
#pragma unroll
    for (int ai = 0; ai < 4; ++ai)
        pa[ai] = Wbf + (size_t)(half * 256 + wid * 64 + ai * 16 + col) * 256 + koff;
#pragma unroll
    for (int bj = 0; bj < 4; ++bj)
        pb[bj] = xbfT + ((size_t)b * N_ + n0 + bj * 16 + col) * TWO_C + half * 256 + koff;

    f32x4 acc[4][4];
#pragma unroll
    for (int ai = 0; ai < 4; ++ai)
#pragma unroll
        for (int bj = 0; bj < 4; ++bj)
            acc[ai][bj] = (f32x4){0.f, 0.f, 0.f, 0.f};

#pragma unroll
    for (int s = 0; s < 8; ++s) {
        bf16x8 af[4], bfr[4];
#pragma unroll
        for (int ai = 0; ai < 4; ++ai) af[ai] = *(const bf16x8*)(pa[ai] + s * 32);
#pragma unroll
        for (int bj = 0; bj < 4; ++bj) bfr[bj] = *(const bf16x8*)(pb[bj] + s * 32);
#pragma unroll
        for (int ai = 0; ai < 4; ++ai)
#pragma unroll
            for (int bj = 0; bj < 4; ++bj)
                acc[ai][bj] = __builtin_amdgcn_mfma_f32_16x16x32_bf16(
                    af[ai], bfr[bj], acc[ai][bj], 0, 0, 0);
    }

    const float* bias = half ? bv2 : bv1;
#pragma unroll
    for (int ai = 0; ai < 4; ++ai) {
        const int cb = wid * 64 + ai * 16 + grp * 4;
#pragma unroll
        for (int r = 0; r < 4; ++r) {
            const float bv = bias[cb + r];
            unsigned short* vr = vstack + ((size_t)b * 512 + half * 256 + cb + r) * N_;
#pragma unroll
            for (int bj = 0; bj < 4; ++bj)
                vr[n0 + bj * 16 + col] = f2bf_rtn(acc[ai][bj][r] + bv);
        }
    }
}

// ---------------------------------------------------------------------------
// Kernel 3: FUSED attention + PV, att written INSIDE the K-loop.
// Pre-pass: E-only sweep (MFMA+exp) -> rowsums -> inv (known before PV loop).
// Main loop step T: {ds_read PV frags} {gld16 A(T+1), sched-pinned first}
// {E(T+1)+exp -> Bsm[nxt] bf16 AND f32 att stores (this ct's 16-col half of
// every tile) scaled by inv} {32 PV MFMA} {vmcnt(4) lgkm(0) + barrier}.
// vmcnt(4): gld16 pair is pinned before the <=4 trailing vmem ops (2 k-loads
// + 2 stores) and fences leave <=4 outstanding, so the drain always covers
// this step's gld16s. The 537 MB att stream overlaps PV MFMA.
// grid = 256 blocks (8b x 2ct x 16nt), 512 threads.
// ---------------------------------------------------------------------------
__global__ __launch_bounds__(512) void fused_pv(
    const unsigned short* __restrict__ qbf,
    const unsigned short* __restrict__ kbf,
    const unsigned short* __restrict__ vstack,
    const float* __restrict__ x1, const float* __restrict__ x2,
    float* __restrict__ out1, float* __restrict__ out2,
    float* __restrict__ att)
{
    __shared__ unsigned short Asm[2][256 * 32];  // 2 x 16 KB, V tile
    __shared__ unsigned short Bsm[2][256 * 32];  // 2 x 16 KB, P tile
    __shared__ float sinv[256];

    const int tid  = threadIdx.x;
    const int lane = tid & 63;
    const int wid  = tid >> 6;
    const int wr   = wid >> 2;      // 0..1 : c-offset *128
    const int wc   = wid & 3;       // 0..3 : n-offset *64
    const int col  = lane & 15;
    const int grp  = lane >> 4;

    // bijective XCD swizzle: nwg=256, 32/XCD -> one batch per XCD
    const int bid  = blockIdx.x;
    const int orig = (bid & 7) * 32 + (bid >> 3);
    const int nt = orig & 15;
    const int ct = (orig >> 4) & 1;
    const int b  = orig >> 5;
    const int n0 = nt * 256;

    const f32x4 zerov = {0.f, 0.f, 0.f, 0.f};

    // q fragments (B-operand of energy MFMA), one per 16-n subtile
    const bf16x8 qf0 = *(const bf16x8*)(qbf + ((size_t)b * N_ + n0 + wid * 32 + col) * 32 + grp * 8);
    const bf16x8 qf1 = *(const bf16x8*)(qbf + ((size_t)b * N_ + n0 + wid * 32 + 16 + col) * 32 + grp * 8);

    const unsigned short* kbase = kbf + ((size_t)b * N_ + col) * 32 + grp * 8;

    // ---- pre-pass: rowsums over all m (E-MFMA + exp only) ----
    float rsum0 = 0.f, rsum1 = 0.f;
    {
        const unsigned short* kq = kbase;
#pragma unroll 2
        for (int T = 0; T < 128; ++T) {
            bf16x8 k0 = *(const bf16x8*)kq;
            bf16x8 k1 = *(const bf16x8*)(kq + 512);
            kq += 1024;
            f32x4 p00 = expv(MF(k0, qf0));
            f32x4 p01 = expv(MF(k1, qf0));
            f32x4 p10 = expv(MF(k0, qf1));
            f32x4 p11 = expv(MF(k1, qf1));
            rsum0 += (p00[0] + p00[1]) + (p00[2] + p00[3])
                   + (p01[0] + p01[1]) + (p01[2] + p01[3]);
            rsum1 += (p10[0] + p10[1]) + (p10[2] + p10[3])
                   + (p11[0] + p11[1]) + (p11[2] + p11[3]);
        }
    }
    rsum0 += __shfl_xor(rsum0, 16); rsum0 += __shfl_xor(rsum0, 32);
    rsum1 += __shfl_xor(rsum1, 16); rsum1 += __shfl_xor(rsum1, 32);
    const float inv0 = 1.f / rsum0;
    const float inv1 = 1.f / rsum1;
    if (lane < 16) {
        sinv[wid * 32 + lane]      = inv0;
        sinv[wid * 32 + 16 + lane] = inv1;
    }
    // visibility guaranteed by the prologue barrier below

    // A (V) staging: pre-swizzled global source, linear LDS dest
    const unsigned short* Vb = vstack + ((size_t)b * 512 + ct * 256) * N_;
    const int q1 = tid + 512;
    const unsigned short* pa0 = Vb + (size_t)(tid >> 2) * N_ + (((tid & 3) ^ ((tid >> 2) & 3)) * 8);
    const unsigned short* pa1 = Vb + (size_t)(q1 >> 2) * N_ + (((q1 & 3) ^ ((q1 >> 2) & 3)) * 8);

    // Bsm write byte-offsets; rows nl0 / nl0+16. (nl&3)==(col&3).
    const int nl0 = wid * 32 + col;
    const int bwA = nl0 * 64 + ((((grp >> 1)) ^ (col & 3)) << 4) + (grp & 1) * 8;
    const int bwB = bwA ^ 32;

    // fragment read byte-offsets
    const int raBase = (wr * 128 + col) * 64 + ((grp ^ (col & 3)) << 4);
    const int rbBase = (wc * 64  + col) * 64 + ((grp ^ (col & 3)) << 4);

    // att store row pointers (this ct's 16-col half of every 32-m tile)
    float* ars0 = att + (size_t)b * N_ * N_ + (size_t)(n0 + wid * 32 + col) * N_
                + ct * 16 + grp * 4;
    float* ars1 = ars0 + (size_t)16 * N_;

    f32x4 acc[8][4];
#pragma unroll
    for (int ai = 0; ai < 8; ++ai)
#pragma unroll
        for (int bj = 0; bj < 4; ++bj)
            acc[ai][bj] = zerov;

#define PACKB(P, BASE, OFF) do {                                              \
    bf16x4 pkv = { (__bf16)(P)[0], (__bf16)(P)[1],                            \
                   (__bf16)(P)[2], (__bf16)(P)[3] };                          \
    *(bf16x4*)((char*)(BASE) + (OFF)) = pkv;                                  \
} while (0)

    // ---- prologue: stage A(0); E(0) -> Bsm[0] + att(T=0); prefetch k(1) ----
    gld16(pa0, &Asm[0][tid * 8]);
    gld16(pa1, &Asm[0][tid * 8 + 4096]);
    pa0 += 32; pa1 += 32;
    __builtin_amdgcn_sched_barrier(0);
    bf16x8 kA0 = *(const bf16x8*)kbase;
    bf16x8 kA1 = *(const bf16x8*)(kbase + 512);
    const unsigned short* kp = kbase + 1024;
    bf16x8 kB0, kB1;
    {
        f32x4 p00 = expv(MF(kA0, qf0));
        f32x4 p01 = expv(MF(kA1, qf0));
        f32x4 p10 = expv(MF(kA0, qf1));
        f32x4 p11 = expv(MF(kA1, qf1));
        kB0 = *(const bf16x8*)kp;
        kB1 = *(const bf16x8*)(kp + 512);
        kp += 1024;
        PACKB(p00, &Bsm[0][0], bwA);
        PACKB(p01, &Bsm[0][0], bwB);
        PACKB(p10, &Bsm[0][0], bwA + 1024);
        PACKB(p11, &Bsm[0][0], bwB + 1024);
        *(f32x4*)ars0 = (ct ? p01 : p00) * inv0;
        *(f32x4*)ars1 = (ct ? p11 : p10) * inv1;
    }
    asm volatile("s_waitcnt vmcnt(4) lgkmcnt(0)" ::: "memory");
    __builtin_amdgcn_s_barrier();
    __builtin_amdgcn_sched_barrier(0);

    auto step = [&](const unsigned short* AsCur, unsigned short* AsNxt,
                    const unsigned short* BsCur, unsigned short* BsNxt,
                    const bf16x8& kc0, const bf16x8& kc1,
                    bf16x8& kn0, bf16x8& kn1, int T, bool doNext) {
        // (1) PV fragment reads for this step
        bf16x8 bfr[4], af0[4], af1[4];
#pragma unroll
        for (int bj = 0; bj < 4; ++bj)
            bfr[bj] = *(const bf16x8*)((const char*)BsCur + rbBase + bj * 1024);
#pragma unroll
        for (int ai = 0; ai < 4; ++ai)
            af0[ai] = *(const bf16x8*)((const char*)AsCur + raBase + ai * 1024);
        // (2) stage A(T) — pinned first in the vmem queue
        if (doNext) {
            gld16(pa0, AsNxt + tid * 8);
            gld16(pa1, AsNxt + tid * 8 + 4096);
            pa0 += 32; pa1 += 32;
        }
        __builtin_amdgcn_sched_barrier(0);
        // (3) E(T) + exp -> Bsm[nxt] bf16 + f32 att stores; prefetch k(T+1)
        if (doNext) {
            f32x4 p00 = expv(MF(kc0, qf0));
            f32x4 p01 = expv(MF(kc1, qf0));
            f32x4 p10 = expv(MF(kc0, qf1));
            f32x4 p11 = expv(MF(kc1, qf1));
            kn0 = *(const bf16x8*)kp;
            kn1 = *(const bf16x8*)(kp + 512);
            kp += 1024;
            PACKB(p00, BsNxt, bwA);
            PACKB(p01, BsNxt, bwB);
            PACKB(p10, BsNxt, bwA + 1024);
            PACKB(p11, BsNxt, bwB + 1024);
            *(f32x4*)(ars0 + (size_t)T * 32) = (ct ? p01 : p00) * inv0;
            *(f32x4*)(ars1 + (size_t)T * 32) = (ct ? p11 : p10) * inv1;
        }
        // (4) PV MFMAs
#pragma unroll
        for (int ai = 0; ai < 4; ++ai)
#pragma unroll
            for (int bj = 0; bj < 4; ++bj)
                acc[ai][bj] = __builtin_amdgcn_mfma_f32_16x16x32_bf16(
                    af0[ai], bfr[bj], acc[ai][bj], 0, 0, 0);
#pragma unroll
        for (int ai = 0; ai < 4; ++ai)
            af1[ai] = *(const bf16x8*)((const char*)AsCur + raBase + (4 + ai) * 1024);
#pragma unroll
        for (int ai = 0; ai < 4; ++ai)
#pragma unroll
            for (int bj = 0; bj < 4; ++bj)
                acc[4 + ai][bj] = __builtin_amdgcn_mfma_f32_16x16x32_bf16(
                    af1[ai], bfr[bj], acc[4 + ai][bj], 0, 0, 0);
        // (5) single fence per step: counted vmcnt keeps stores/k in flight
        if (doNext) {
            asm volatile("s_waitcnt vmcnt(4) lgkmcnt(0)" ::: "memory");
            __builtin_amdgcn_s_barrier();
            __builtin_amdgcn_sched_barrier(0);
        }
    };

    for (int tt = 0; tt < 64; ++tt) {
        step(&Asm[0][0], &Asm[1][0], &Bsm[0][0], &Bsm[1][0], kB0, kB1, kA0, kA1,
             2 * tt + 1, true);
        step(&Asm[1][0], &Asm[0][0], &Bsm[1][0], &Bsm[0][0], kA0, kA1, kB0, kB1,
             2 * tt + 2, tt < 63);
    }

    // ---- epilogue: out = acc * inv + x ----
    __syncthreads();
    float* outp     = ct ? out2 : out1;
    const float* xp = ct ? x2 : x1;
    float sc[4];
#pragma unroll
    for (int bj = 0; bj < 4; ++bj) sc[bj] = sinv[wc * 64 + bj * 16 + col];
#pragma unroll
    for (int ai = 0; ai < 8; ++ai) {
        const int c_l = wr * 128 + ai * 16 + grp * 4;
#pragma unroll
        for (int bj = 0; bj < 4; ++bj) {
            const int n = n0 + wc * 64 + bj * 16 + col;
#pragma unroll
            for (int r = 0; r < 4; ++r) {
                const size_t idx = ((size_t)b * C_ + c_l + r) * N_ + n;
                outp[idx] = acc[ai][bj][r] * sc[bj] + xp[idx];
            }
        }
    }
#undef PACKB
}

// ---------------------------------------------------------------------------
extern "C" void kernel_launch(void* const* d_in, const int* in_sizes, int n_in,
                              void* d_out, int out_size, void* d_ws, size_t ws_size,
                              hipStream_t stream)
{
    const float* x1  = (const float*)d_in[0];
    const float* x2  = (const float*)d_in[1];
    const float* Wq  = (const float*)d_in[2];
    const float* bq  = (const float*)d_in[3];
    const float* Wk  = (const float*)d_in[4];
    const float* bk  = (const float*)d_in[5];
    const float* Wv1 = (const float*)d_in[6];
    const float* bv1 = (const float*)d_in[7];
    const float* Wv2 = (const float*)d_in[8];
    const float* bv2 = (const float*)d_in[9];

    float* out  = (float*)d_out;
    float* out1 = out;
    float* out2 = out + (size_t)B_ * C_ * N_;
    float* att  = out + 2 * (size_t)B_ * C_ * N_;

    // xbfT (32 MB) scribbles the front of the att region; fused_pv
    // fully overwrites all of att afterwards.
    unsigned short* xbfT = (unsigned short*)att;

    char* ws = (char*)d_ws;
    unsigned short* qbf = (unsigned short*)ws;                                  // 2 MB [B][N][32]
    unsigned short* kbf = (unsigned short*)(ws + (size_t)2 * 1024 * 1024);      // 2 MB
    unsigned short* vstack = (unsigned short*)(ws + (size_t)4 * 1024 * 1024);   // 32 MB
    float* pq = (float*)(ws + (size_t)36 * 1024 * 1024);                        // 8 MB
    float* pk = (float*)(ws + (size_t)44 * 1024 * 1024);                        // 8 MB
    unsigned short* Wbf = (unsigned short*)(ws + (size_t)52 * 1024 * 1024);     // 256 KB

    wconv<<<64, 256, 0, stream>>>(Wv1, Wv2, Wbf);
    qk_part<<<B_ * 16 * 4, 256, 0, stream>>>(x1, x2, Wq, Wk, pq, pk, xbfT);
    qk_reduce<<<(B_ * N_ * 4) / 256, 256, 0, stream>>>(pq, pk, bq, bk, qbf, kbf);
    v_mfma<<<B_ * 2 * 64, 256, 0, stream>>>(Wbf, xbfT, bv1, bv2, vstack);
    fused_pv<<<256, 512, 0, stream>>>(qbf, kbf, vstack, x1, x2, out1, out2, att);
}